// Round 5
// baseline (233.922 us; speedup 1.0000x reference)
//
#include <hip/hip_runtime.h>
#include <hip/hip_bf16.h>
#include <stdint.h>

// Problem: B=4096, I=H=1024. pre_ih = x@w_ih^T, pre_hh = h@w_hh^T (each 4096x4096,
// K=1024), per-gate LN over H, gate math, c_new LN, outputs h_new||c_new (fp32).

#define HDIM 1024
#define BATCH 4096
#define NGATE 4096   /* 4*H */
#define KDIM 1024

typedef __bf16 bf16x8 __attribute__((ext_vector_type(8)));
typedef float f32x4 __attribute__((ext_vector_type(4)));
typedef unsigned short ushort8_t __attribute__((ext_vector_type(8)));

__device__ __forceinline__ unsigned short f2bf(float f) {
  unsigned int u = __builtin_bit_cast(unsigned int, f);
  unsigned int r = (u + 0x7fffu + ((u >> 16) & 1u)) >> 16;
  return (unsigned short)r;
}

__device__ __forceinline__ float bf2f(unsigned short s) {
  unsigned int u = ((unsigned int)s) << 16;
  return __builtin_bit_cast(float, u);
}

__device__ __forceinline__ void gl_lds16(const void* g, void* l) {
  // async global->LDS, 16B per lane; LDS dest = wave-uniform base + lane*16,
  // global addr is per-lane.
  __builtin_amdgcn_global_load_lds(
      (__attribute__((address_space(1))) unsigned int*)g,
      (__attribute__((address_space(3))) unsigned int*)l,
      16, 0, 0);
}

#define BAR() asm volatile("s_barrier" ::: "memory")
#define WAITL() asm volatile("s_waitcnt lgkmcnt(0)" ::: "memory")
#define WAITV(N) asm volatile("s_waitcnt vmcnt(" #N ")" ::: "memory")
#define SCHED0() __builtin_amdgcn_sched_barrier(0)

// ---------------- cast fp32 -> bf16 (x, h, w_ih, w_hh) ----------------
// Grid-stride: 512 blocks x 4 arrays, 32 elems/thread, 32B loads + 16B stores.
__global__ __launch_bounds__(256) void cast_bf16_kernel(
    const float* __restrict__ x, const float* __restrict__ h,
    const float* __restrict__ wi, const float* __restrict__ wh,
    unsigned short* __restrict__ xb, unsigned short* __restrict__ hb,
    unsigned short* __restrict__ wib, unsigned short* __restrict__ whb) {
  const float* src;
  unsigned short* dst;
  switch (blockIdx.y) {
    case 0: src = x;  dst = xb;  break;
    case 1: src = h;  dst = hb;  break;
    case 2: src = wi; dst = wib; break;
    default: src = wh; dst = whb; break;
  }
  size_t base = ((size_t)blockIdx.x * 256 + threadIdx.x) * 8;
  const size_t stride = (size_t)512 * 256 * 8;  // 1M elems per sweep
#pragma unroll
  for (int it = 0; it < 4; ++it) {
    float4 v0 = *(const float4*)(src + base);
    float4 v1 = *(const float4*)(src + base + 4);
    ushort8_t o;
    o[0] = f2bf(v0.x); o[1] = f2bf(v0.y); o[2] = f2bf(v0.z); o[3] = f2bf(v0.w);
    o[4] = f2bf(v1.x); o[5] = f2bf(v1.y); o[6] = f2bf(v1.z); o[7] = f2bf(v1.w);
    *(ushort8_t*)(dst + base) = o;
    base += stride;
  }
}

// ---------------- bf16 MFMA GEMM: C[m][n] = sum_k A[m][k]*B[n][k] ----------------
// 256x256 tile, BK=64, 8 waves (2M x 4N), 8-phase/2-K-tile deep-pipelined
// schedule. Round-4 failed because stages at p1/p2 clobbered slots (As[3],
// Bs[2]) still read at p7/p5 of the SAME iteration. This version re-derives
// the schedule under two audited invariants:
//   (I1) slot lifetime: a stage targeting slot S issues >=1 phase after S's
//        last ds_read (the intervening BAR->WAITL->BAR proves all waves'
//        reads of S completed before the stage instruction even issues).
//   (I2) wait depth: with 2 loads/stage in per-wave order and in-order vmcnt
//        completion, each WAITV(8) at ends of p2/p4/p6/p8 forces exactly the
//        two stages issued 4-5 phases (~1400-1750cy) earlier -> >= HBM miss
//        latency -> zero expected stall (rounds 1-2 stalled on 1-phase-old
//        stages 3x/K-tile; that was the 91-101us regression).
// Gray-coded quadrants per K-tile: q0(A0,B0) q1(A0,B1) q2(A1,B1) q3(A1,B0);
// fragments persist in regs: 24 ds_read_b128/wave/K-tile, q3/q7 have none.
//
// Slots: As[0]=A0E As[1]=A1E As[2]=A0O As[3]=A1O (E=even k-tile, O=odd); same
// for Bs. Per-iter stage order (target slot freed in the previous phase):
//   p1:A1(O)->As[3]   p2:A0(E+2)->As[0]  p3:B0(E+2)->Bs[0]  p4:B1(E+2)->Bs[1]
//   p5:A1(E+2)->As[1] p6:A0(O+2)->As[2]  p7:B0(O+2)->Bs[2]  p8:B1(O+2)->Bs[3]
// Read coverage (read <- producer, forcing wait): p1<-p2/p3 prev (end-p6/p8
// prev); p2<-p4 prev (end-p8 prev); p3<-p5 prev (end-p2); p5<-p6/p7 prev
// (end-p2/p4); p6<-p8 prev (end-p4); p7<-p1 cur (end-p6). All >=4 phases deep.
// Prologue: 7 stages + WAITV(6) (forces first 4) -> same invariant at u=0.
// Tail stages wrap k (&15) into freed slots; garbage never read; WAITV(0).
__global__ __launch_bounds__(512, 2) void gemm_bt_kernel(
    const unsigned short* __restrict__ A0p, const unsigned short* __restrict__ B0p,
    unsigned short* __restrict__ C0p,
    const unsigned short* __restrict__ A1p, const unsigned short* __restrict__ B1p,
    unsigned short* __restrict__ C1p) {
  // T1: flat id -> XCD-contiguous remap (512 = 8 XCDs x 64 blocks, bijective)
  const int flat = blockIdx.x + (blockIdx.y << 4) + (blockIdx.z << 8);
  const int swz = ((flat & 7) << 6) | (flat >> 3);
  const int bz = swz >> 8;
  const unsigned short* A = bz ? A1p : A0p;
  const unsigned short* B = bz ? B1p : B0p;
  unsigned short* C = bz ? C1p : C0p;
  const int bm = (swz & 15) * 256;
  const int bn = ((swz >> 4) & 15) * 256;

  __shared__ alignas(16) unsigned short As[4 * 8192];  // 4 half-slots [128][64]
  __shared__ alignas(16) unsigned short Bs[4 * 8192];

  const int tid = threadIdx.x;
  const int wave = tid >> 6;
  const int lane = tid & 63;
  const int wr = wave >> 2;   // 0..1 (M)
  const int wc = wave & 3;    // 0..3 (N)

  const int srow = lane >> 3;
  const int scol = ((lane & 7) ^ (lane >> 3)) * 8;  // fetch-side swizzle
  const int m15 = lane & 15;
  const int quad = lane >> 4;
  const int sw = m15 & 7;

  const unsigned short* gwA = A + (size_t)(bm + wave * 8 + srow) * KDIM + scol;
  const unsigned short* gwB = B + (size_t)(bn + wave * 8 + srow) * KDIM + scol;

  f32x4 acc[8][4];
#pragma unroll
  for (int i = 0; i < 8; ++i)
#pragma unroll
    for (int j = 0; j < 4; ++j)
#pragma unroll
      for (int r = 0; r < 4; ++r) acc[i][j][r] = 0.0f;

  // stage one 128-row half (global rows goff..goff+127, cols kk..kk+63)
  auto stage = [&](const unsigned short* gw, int goff, int kk, unsigned short* slot) {
    gl_lds16(gw + (size_t)goff * KDIM + kk, slot + wave * 512);
    gl_lds16(gw + (size_t)(goff + 64) * KDIM + kk, slot + wave * 512 + 4096);
  };

  bf16x8 af[4][2], b0[2][2], b1[2][2];

  auto ldA = [&](const unsigned short* base) {
#pragma unroll
    for (int i2 = 0; i2 < 4; ++i2) {
      int r = wr * 64 + i2 * 16 + m15;
#pragma unroll
      for (int s = 0; s < 2; ++s)
        af[i2][s] = *(const bf16x8*)&base[r * 64 + (((s * 4 + quad) ^ sw) << 3)];
    }
  };
  auto ldB = [&](const unsigned short* base, bf16x8 (&bf)[2][2]) {
#pragma unroll
    for (int j2 = 0; j2 < 2; ++j2) {
      int r = wc * 32 + j2 * 16 + m15;
#pragma unroll
      for (int s = 0; s < 2; ++s)
        bf[j2][s] = *(const bf16x8*)&base[r * 64 + (((s * 4 + quad) ^ sw) << 3)];
    }
  };

#define MMA16(H, G, BF)                                                       \
  do {                                                                        \
    __builtin_amdgcn_s_setprio(1);                                            \
    _Pragma("unroll") for (int i2 = 0; i2 < 4; ++i2)                          \
        _Pragma("unroll") for (int j2 = 0; j2 < 2; ++j2) {                    \
      acc[(H)*4 + i2][(G)*2 + j2] = __builtin_amdgcn_mfma_f32_16x16x32_bf16(  \
          af[i2][0], BF[j2][0], acc[(H)*4 + i2][(G)*2 + j2], 0, 0, 0);        \
      acc[(H)*4 + i2][(G)*2 + j2] = __builtin_amdgcn_mfma_f32_16x16x32_bf16(  \
          af[i2][1], BF[j2][1], acc[(H)*4 + i2][(G)*2 + j2], 0, 0, 0);        \
    }                                                                         \
    __builtin_amdgcn_s_setprio(0);                                            \
  } while (0)

  // ---- prologue: 7 stages (deadline order), force first 4 resident ----
  stage(gwA, 0,   0,  &As[0]);            // 1: A0(0)  read p1
  stage(gwB, 0,   0,  &Bs[0]);            // 2: B0(0)  read p1
  stage(gwB, 128, 0,  &Bs[1 * 8192]);     // 3: B1(0)  read p2
  stage(gwA, 128, 0,  &As[1 * 8192]);     // 4: A1(0)  read p3
  stage(gwA, 0,   64, &As[2 * 8192]);     // 5: A0(1)  read p5 (forced end-p2)
  stage(gwB, 0,   64, &Bs[2 * 8192]);     // 6: B0(1)  read p5 (forced end-p4)
  stage(gwB, 128, 64, &Bs[3 * 8192]);     // 7: B1(1)  read p6 (forced end-p4)
  WAITV(6);   // force stages 1-4; leave 5,6,7 (6 loads) in flight
  BAR();

  for (int u = 0; u < 8; ++u) {
    const int kO1 = ((2 * u + 1) & 15) * 64;  // tile O   (A1O: staged p1, read p7)
    const int kE2 = ((2 * u + 2) & 15) * 64;  // tiles E+2 (wrap: garbage, unread)
    const int kO2 = ((2 * u + 3) & 15) * 64;  // tiles O+2

    // ===== p1: E.q0 (A0E,B0E) ===== stage A1(O)->As[3] (freed p7 prev)
    ldA(&As[0]);
    ldB(&Bs[0], b0);
    stage(gwA, 128, kO1, &As[3 * 8192]);
    BAR(); WAITL(); SCHED0();
    MMA16(0, 0, b0);
    BAR();

    // ===== p2: E.q1 (A0E,B1E) ===== stage A0(E+2)->As[0] (freed p1)
    ldB(&Bs[1 * 8192], b1);
    stage(gwA, 0, kE2, &As[0]);
    BAR(); WAITL(); SCHED0();
    MMA16(0, 1, b1);
    WAITV(8);   // forces stages 4-5 phases old (A1E-producer etc.)
    BAR();

    // ===== p3: E.q2 (A1E,B1E) ===== stage B0(E+2)->Bs[0] (freed p1)
    ldA(&As[1 * 8192]);
    stage(gwB, 0, kE2, &Bs[0]);
    BAR(); WAITL(); SCHED0();
    MMA16(1, 1, b1);
    BAR();

    // ===== p4: E.q3 (A1E,B0E) — regs only ===== stage B1(E+2)->Bs[1] (freed p2)
    stage(gwB, 128, kE2, &Bs[1 * 8192]);
    BAR();
    MMA16(1, 0, b0);
    WAITV(8);
    BAR();

    // ===== p5: O.q0 (A0O,B0O) ===== stage A1(E+2)->As[1] (freed p3)
    ldA(&As[2 * 8192]);
    ldB(&Bs[2 * 8192], b0);
    stage(gwA, 128, kE2, &As[1 * 8192]);
    BAR(); WAITL(); SCHED0();
    MMA16(0, 0, b0);
    BAR();

    // ===== p6: O.q1 (A0O,B1O) ===== stage A0(O+2)->As[2] (freed p5)
    ldB(&Bs[3 * 8192], b1);
    stage(gwA, 0, kO2, &As[2 * 8192]);
    BAR(); WAITL(); SCHED0();
    MMA16(0, 1, b1);
    WAITV(8);   // forces p1,p2 of this iter (A1(O) needed at p7)
    BAR();

    // ===== p7: O.q2 (A1O,B1O) ===== stage B0(O+2)->Bs[2] (freed p5)
    ldA(&As[3 * 8192]);
    stage(gwB, 0, kO2, &Bs[2 * 8192]);
    BAR(); WAITL(); SCHED0();
    MMA16(1, 1, b1);
    BAR();

    // ===== p8: O.q3 (A1O,B0O) — regs only ===== stage B1(O+2)->Bs[3] (freed p6)
    stage(gwB, 128, kO2, &Bs[3 * 8192]);
    BAR();
    MMA16(1, 0, b0);
    WAITV(8);
    BAR();
  }
  WAITV(0);  // drain tail wrap-stages

  // D layout per 16x16 frag: row = quad*4 + rr, col = m15  [m89/m91 verified]
#pragma unroll
  for (int i = 0; i < 8; ++i) {
    int m = bm + (i >> 2) * 128 + wr * 64 + (i & 3) * 16 + quad * 4;
#pragma unroll
    for (int j = 0; j < 4; ++j) {
      int n = bn + (j >> 1) * 128 + wc * 32 + (j & 1) * 16 + m15;
#pragma unroll
      for (int rr = 0; rr < 4; ++rr)
        C[(size_t)(m + rr) * NGATE + n] = f2bf(acc[i][j][rr]);
    }
  }
#undef MMA16
}

// ---------------- LN + gates + cell update ----------------
// One block per batch row b. Phase A: wave g owns gate g; lane owns h-positions
// lane*4 + s*256 (s=0..3). Full 64-lane butterfly gives ALL lanes the LN stats
// (no LDS stats round-trip), normalize in-register, hand normalized gate values
// to phase B via a 16KB LDS buffer (fully contiguous b128 writes/reads -- no
// bank conflicts). Phase B: thread t owns h = t*4..t*4+3 across all 4 gates;
// cell math + one block reduction for the c_new LN. 2 syncthreads total.
__device__ __forceinline__ float fast_sigmoid(float x) {
  return __builtin_amdgcn_rcpf(1.0f + __expf(-x));
}
__device__ __forceinline__ float fast_tanh(float x) {
  // 1 - 2/(exp(2x)+1); exp->inf gives 1, exp->0 gives -1 (correct saturation)
  return 1.0f - 2.0f * __builtin_amdgcn_rcpf(__expf(2.0f * x) + 1.0f);
}

__global__ __launch_bounds__(256) void ln_gate_kernel(
    const unsigned short* __restrict__ pih, const unsigned short* __restrict__ phh,
    const float* __restrict__ c, const float* __restrict__ b_ih,
    const float* __restrict__ gamma, const float* __restrict__ beta,
    float* __restrict__ h_out, float* __restrict__ c_out) {
  __shared__ float gbuf[4][1024];  // normalized gate values (16 KB)
  __shared__ float red[8];         // c_new LN cross-wave partials
  const int b = blockIdx.x;
  const int t = threadIdx.x;
  const int g = t >> 6;    // wave index = gate index in phase A
  const int lane = t & 63;
  const float inv_h = 1.0f / 1024.0f;
  const float eps = 1e-5f;

  // ---- Phase A: per-gate LN stats + normalize, wave-local ----
  {
    const size_t rb = (size_t)b * NGATE + g * HDIM;
    float vih[16], vhh[16];
    float s0 = 0.f, q0 = 0.f, s1 = 0.f, q1 = 0.f;
#pragma unroll
    for (int s = 0; s < 4; ++s) {
      const int hh = lane * 4 + s * 256;
      ushort4 a4 = *(const ushort4*)&pih[rb + hh];
      ushort4 e4 = *(const ushort4*)&phh[rb + hh];
      vih[s * 4 + 0] = bf2f(a4.x); vih[s * 4 + 1] = bf2f(a4.y);
      vih[s * 4 + 2] = bf2f(a4.z); vih[s * 4 + 3] = bf2f(a4.w);
      vhh[s * 4 + 0] = bf2f(e4.x); vhh[s * 4 + 1] = bf2f(e4.y);
      vhh[s * 4 + 2] = bf2f(e4.z); vhh[s * 4 + 3] = bf2f(e4.w);
#pragma unroll
      for (int r = 0; r < 4; ++r) {
        float va = vih[s * 4 + r], ea = vhh[s * 4 + r];
        s0 += va; q0 += va * va;
        s1 += ea; q1 += ea * ea;
      }
    }
#pragma unroll
    for (int o = 1; o < 64; o <<= 1) {
      s0 += __shfl_xor(s0, o, 64); q0 += __shfl_xor(q0, o, 64);
      s1 += __shfl_xor(s1, o, 64); q1 += __shfl_xor(q1, o, 64);
    }
    const float mu0 = s0 * inv_h;
    const float rs0 = rsqrtf(q0 * inv_h - mu0 * mu0 + eps);
    const float mu1 = s1 * inv_h;
    const float rs1 = rsqrtf(q1 * inv_h - mu1 * mu1 + eps);

#pragma unroll
    for (int s = 0; s < 4; ++s) {
      const int hh = lane * 4 + s * 256;
      float4 g0 = *(const float4*)&gamma[(2 * g) * HDIM + hh];
      float4 b0 = *(const float4*)&beta[(2 * g) * HDIM + hh];
      float4 g1 = *(const float4*)&gamma[(2 * g + 1) * HDIM + hh];
      float4 b1 = *(const float4*)&beta[(2 * g + 1) * HDIM + hh];
      float4 bb = *(const float4*)&b_ih[g * HDIM + hh];
      const float* g0p = &g0.x; const float* b0p = &b0.x;
      const float* g1p = &g1.x; const float* b1p = &b1.x;
      const float* bbp = &bb.x;
      float4 out;
      float* op = &out.x;
#pragma unroll
      for (int r = 0; r < 4; ++r) {
        float gih = g0p[r] * ((vih[s * 4 + r] - mu0) * rs0) + b0p[r];
        float ghh = g1p[r] * ((vhh[s * 4 + r] - mu1) * rs1) + b1p[r];
        op[r] = gih + ghh + bbp[r];
      }
      *(float4*)&gbuf[g][hh] = out;  // contiguous across lanes: conflict-free
    }
  }
  __syncthreads();

  // ---- Phase B: gate math + c_new LN ----
  const int j = t * 4;
  float4 iv4 = *(const float4*)&gbuf[0][j];
  float4 fv4 = *(const float4*)&gbuf[1][j];
  float4 av4 = *(const float4*)&gbuf[2][j];
  float4 ov4 = *(const float4*)&gbuf[3][j];
  const float* ivp = &iv4.x; const float* fvp = &fv4.x;
  const float* avp = &av4.x; const float* ovp = &ov4.x;

  float4 cv4 = *(const float4*)&c[(size_t)b * HDIM + j];
  const float* cvp = &cv4.x;
  float cn[4], ov[4];
  float s2 = 0.f, q2 = 0.f;
#pragma unroll
  for (int r = 0; r < 4; ++r) {
    float iv = fast_sigmoid(ivp[r]);
    float fv = fast_sigmoid(fvp[r]);
    float av = fast_tanh(avp[r]);
    ov[r] = fast_sigmoid(ovp[r]);
    float cvn = fv * cvp[r] + iv * av;
    cn[r] = cvn;
    s2 += cvn; q2 += cvn * cvn;
  }
#pragma unroll
  for (int o = 1; o < 64; o <<= 1) {
    s2 += __shfl_xor(s2, o, 64);
    q2 += __shfl_xor(q2, o, 64);
  }
  if (lane == 0) { red[g * 2] = s2; red[g * 2 + 1] = q2; }
  __syncthreads();
  s2 = red[0] + red[2] + red[4] + red[6];
  q2 = red[1] + red[3] + red[5] + red[7];
  float mu = s2 * inv_h;
  float rs = rsqrtf(q2 * inv_h - mu * mu + eps);

  float4 g8 = *(const float4*)&gamma[8 * HDIM + j];
  float4 b8 = *(const float4*)&beta[8 * HDIM + j];
  const float* g8p = &g8.x; const float* b8p = &b8.x;
  float4 ho, co;
  float* hop = &ho.x; float* cop = &co.x;
#pragma unroll
  for (int r = 0; r < 4; ++r) {
    float ln = g8p[r] * ((cn[r] - mu) * rs) + b8p[r];
    hop[r] = ov[r] * fast_tanh(ln);
    cop[r] = cn[r];
  }
  *(float4*)&h_out[(size_t)b * HDIM + j] = ho;
  *(float4*)&c_out[(size_t)b * HDIM + j] = co;
}

extern "C" void kernel_launch(void* const* d_in, const int* in_sizes, int n_in,
                              void* d_out, int out_size, void* d_ws, size_t ws_size,
                              hipStream_t stream) {
  const float* x     = (const float*)d_in[0];
  const float* h     = (const float*)d_in[1];
  const float* c     = (const float*)d_in[2];
  const float* w_ih  = (const float*)d_in[3];
  const float* w_hh  = (const float*)d_in[4];
  const float* b_ih  = (const float*)d_in[5];
  const float* gamma = (const float*)d_in[6];
  const float* beta  = (const float*)d_in[7];
  // d_in[8] = time (unused)

  // workspace layout (bytes):
  //   0    xb  bf16 4096x1024 (8MB) | 8M hb | 16M wib | 24M whb
  //   32M  pih bf16 4096x4096 (32MB) | 64M phh (32MB)   total 96 MB
  char* ws = (char*)d_ws;
  unsigned short* xb  = (unsigned short*)(ws);
  unsigned short* hb  = (unsigned short*)(ws + (size_t)8 * 1024 * 1024);
  unsigned short* wib = (unsigned short*)(ws + (size_t)16 * 1024 * 1024);
  unsigned short* whb = (unsigned short*)(ws + (size_t)24 * 1024 * 1024);
  unsigned short* pih = (unsigned short*)(ws + (size_t)32 * 1024 * 1024);
  unsigned short* phh = (unsigned short*)(ws + (size_t)64 * 1024 * 1024);

  dim3 cgrid(512, 4, 1);   // grid-stride: 4 arrays x 4M elems, 32 elems/thread
  cast_bf16_kernel<<<cgrid, 256, 0, stream>>>(x, h, w_ih, w_hh, xb, hb, wib, whb);

  dim3 ggrid(16, 16, 2);   // 256x256 tiles over 4096x4096; z: 0=ih, 1=hh
  gemm_bt_kernel<<<ggrid, 512, 0, stream>>>(xb, wib, pih, hb, whb, phh);

  float* h_out = (float*)d_out;
  float* c_out = h_out + (size_t)BATCH * HDIM;
  ln_gate_kernel<<<4096, 256, 0, stream>>>(pih, phh, c, b_ih, gamma, beta, h_out, c_out);
}